// Round 6
// baseline (774.772 us; speedup 1.0000x reference)
//
#include <hip/hip_runtime.h>
#include <math.h>

#define BSZ  2
#define CDIM 256
#define NDIM 4096
#define SHIFT 110.0f

typedef _Float16 f16;
typedef f16  f16x8 __attribute__((ext_vector_type(8)));
typedef float f32x4 __attribute__((ext_vector_type(4)));

// ---------------- memory layout ----------------
// workspace: Ah_q (4MB) | Al_q (4MB) | Bex (4MB) | floats: v_ex, v_q
// e2q operands (Ah_e, Al_e, Bq) parked at the START of the A_q2e output
// region: fully consumed by flash(e2q) BEFORE flash(q2e) writes A_q2e.
static const size_t F16N   = (size_t)BSZ * NDIM * CDIM;       // 2097152 elems
static const size_t WS_FB  = 3 * F16N / 2;                    // float offset after 3 f16 arrays

// ---------------------------------------------------------------------------
// corr kernel: corr[b][m][cc] = sum_c feat[b][c][m] * W[cc][c]
// writes split fp16: Ah[b][m][cc] (hi) and Al (residual), cc contiguous.
// ---------------------------------------------------------------------------
__global__ __launch_bounds__(256) void corr_kernel(
    const float* __restrict__ ex, const float* __restrict__ q,
    const float* __restrict__ W_ex, const float* __restrict__ W_q,
    f16* __restrict__ Ah_e, f16* __restrict__ Al_e,
    f16* __restrict__ Ah_q, f16* __restrict__ Al_q)
{
    const int z   = blockIdx.z;
    const int sel = z >> 1;
    const int b   = z & 1;
    const float* feat = sel ? q   : ex;
    const float* W    = sel ? W_q : W_ex;
    f16* Ah = sel ? Ah_q : Ah_e;
    f16* Al = sel ? Al_q : Al_e;

    const int m0  = blockIdx.x * 128;
    const int cc0 = blockIdx.y * 128;
    const int t   = threadIdx.x;
    const int tx  = t & 15;       // cc microtile
    const int ty  = t >> 4;       // m microtile

    __shared__ float sA[8][128];  // feat[k][m]
    __shared__ float sB[8][128];  // W[k][cc]

    float acc[8][8];
#pragma unroll
    for (int i = 0; i < 8; i++)
#pragma unroll
        for (int j = 0; j < 8; j++) acc[i][j] = 0.f;

    for (int k0 = 0; k0 < CDIM; k0 += 8) {
        {   // sA: feat[(b*C + k0+kk)*N + m0+mi], contiguous in m
            int kk = t >> 5, mi = (t & 31) * 4;
            *(float4*)(&sA[kk][mi]) =
                *(const float4*)(feat + ((size_t)(b * CDIM + k0 + kk)) * NDIM + m0 + mi);
        }
        {   // sB: W[(cc0+ccj)*C + k0+kkb..+3] -> scatter transposed
            int ccj = t >> 1, kkb = (t & 1) * 4;
            float4 f = *(const float4*)(W + (size_t)(cc0 + ccj) * CDIM + k0 + kkb);
            sB[kkb + 0][ccj] = f.x; sB[kkb + 1][ccj] = f.y;
            sB[kkb + 2][ccj] = f.z; sB[kkb + 3][ccj] = f.w;
        }
        __syncthreads();
#pragma unroll
        for (int kk = 0; kk < 8; kk++) {
            float a[8], bb[8];
            *(float4*)(a)      = *(const float4*)(&sA[kk][ty * 8]);
            *(float4*)(a + 4)  = *(const float4*)(&sA[kk][ty * 8 + 4]);
            *(float4*)(bb)     = *(const float4*)(&sB[kk][tx * 8]);
            *(float4*)(bb + 4) = *(const float4*)(&sB[kk][tx * 8 + 4]);
#pragma unroll
            for (int i = 0; i < 8; i++)
#pragma unroll
                for (int j = 0; j < 8; j++)
                    acc[i][j] = fmaf(a[i], bb[j], acc[i][j]);
        }
        __syncthreads();
    }
#pragma unroll
    for (int i = 0; i < 8; i++) {
        const int m = m0 + ty * 8 + i;
        f16x8 hv, lv;
#pragma unroll
        for (int j = 0; j < 8; j++) {
            float x = acc[i][j];
            f16 hh = (f16)x;
            hv[j] = hh;
            lv[j] = (f16)(x - (float)hh);
        }
        const size_t off = ((size_t)(b * NDIM + m)) * CDIM + cc0 + tx * 8;
        *(f16x8*)(Ah + off) = hv;
        *(f16x8*)(Al + off) = lv;
    }
}

// ---------------------------------------------------------------------------
// pack_b: Bpk[b][n][c] = fp16(feat[b][c][n])   (transpose via LDS)
// ---------------------------------------------------------------------------
__global__ __launch_bounds__(256) void pack_b_kernel(
    const float* __restrict__ ex, const float* __restrict__ q,
    f16* __restrict__ Bq, f16* __restrict__ Bex)
{
    const int z   = blockIdx.z;
    const int sel = z >> 1;
    const int b   = z & 1;
    const float* feat = sel ? ex : q;   // sel0: q -> Bq (e2q key), sel1: ex -> Bex
    f16* outp         = sel ? Bex : Bq;

    const int n0 = blockIdx.x * 64, c0 = blockIdx.y * 64;
    __shared__ float sT[64][65];
    const int t = threadIdx.x;
    const int tn = t & 63, tr = t >> 6;
#pragma unroll
    for (int r = 0; r < 16; ++r) {
        int c = tr + r * 4;
        sT[c][tn] = feat[((size_t)(b * CDIM + c0 + c)) * NDIM + n0 + tn];
    }
    __syncthreads();
#pragma unroll
    for (int r = 0; r < 16; ++r) {
        int n = tr + r * 4;
        outp[((size_t)(b * NDIM + n0 + n)) * CDIM + c0 + tn] = (f16)sT[tn][n];
    }
}

// ---------------------------------------------------------------------------
// v kernel: v[b][n] = sum_c g[c] * feat[b][c][n]
// ---------------------------------------------------------------------------
__global__ __launch_bounds__(256) void v_kernel(
    const float* __restrict__ ex, const float* __restrict__ q,
    const float* __restrict__ g,
    float* __restrict__ v_ex, float* __restrict__ v_q)
{
    __shared__ float sg[CDIM];
    const int t = threadIdx.x;
    sg[t] = g[t];
    __syncthreads();

    const int sel = blockIdx.z;
    const int b   = blockIdx.y;
    const float* feat = sel ? q : ex;
    float* outp       = sel ? v_q : v_ex;

    const int n = blockIdx.x * 256 + t;
    float acc = 0.f;
    for (int c = 0; c < CDIM; c++)
        acc = fmaf(sg[c], feat[((size_t)(b * CDIM + c)) * NDIM + n], acc);
    outp[b * NDIM + n] = acc;
}

// ---------------------------------------------------------------------------
// flash score kernel (block-local two-pass softmax, no atomics, no rescale):
// Block owns m-tile of 16 rows x ALL n (4096). 4 waves split n into quarters.
// A-frags (16 m x 256 k, hi+lo fp16) live in 64 VGPRs across both passes.
// Pass 1: stream B (pair-pipelined register prefetch), MFMA, exp, accumulate
//         rowsum/rowdot in regs -> shuffle + tiny-LDS block reduce -> inv,
//         mask written directly.
// Pass 2: re-stream B, recompute S, store A = exp(S-SHIFT)*iv (normalized,
//         transposed layout out[b][n][m], full 64B segments per instr).
// Grid (256, B); XCD-pair swizzle: blocks x and x+8 (same XCD slot) process
// adjacent m-tiles 2p, 2p+1 so both halves of each 128B output line are
// written concurrently on the SAME XCD (no half-dirty-line inflation).
// ---------------------------------------------------------------------------
__global__ __launch_bounds__(256, 2) void flash_score_kernel(
    const f16* __restrict__ Ah, const f16* __restrict__ Al,
    const f16* __restrict__ Bp, const float* __restrict__ v,
    float* __restrict__ outA, float* __restrict__ outMask)
{
    const int bb = blockIdx.y;
    const int x  = blockIdx.x;
    const int gpair = ((x >> 4) << 3) + (x & 7);       // pair index 0..127
    const int m0 = (gpair * 2 + ((x >> 3) & 1)) * 16;  // m-tile base

    const int t = threadIdx.x, lane = t & 63, wv = t >> 6;
    const int lq = lane >> 4, ll = lane & 15;

    // ---- A fragments for full K, held in registers through both passes ----
    const size_t aoff = ((size_t)(bb * NDIM + m0 + ll)) * CDIM + lq * 8;
    f16x8 ah[8], al[8];
#pragma unroll
    for (int s = 0; s < 8; ++s) {
        ah[s] = *(const f16x8*)(Ah + aoff + s * 32);
        al[s] = *(const f16x8*)(Al + aoff + s * 32);
    }

    const f16*   bpw = Bp + ((size_t)(bb * NDIM + wv * 1024 + ll)) * CDIM + lq * 8;
    const float* vp  = v + bb * NDIM + wv * 1024 + ll;
    float*       outw = outA + ((size_t)(bb * NDIM + wv * 1024 + ll)) * NDIM + m0 + lq * 4;

    f16x8 bx[16], by[16];            // pair buffers (2 n-frags each)
    float rs[4] = {0.f, 0.f, 0.f, 0.f}, rd[4] = {0.f, 0.f, 0.f, 0.f};
    float iv[4];

#define LOADP(buf_, nf_) do {                                                 \
        const f16* _p0 = bpw + (size_t)(nf_) * 16 * CDIM;                     \
        const f16* _p1 = _p0 + 16 * CDIM;                                     \
        _Pragma("unroll")                                                     \
        for (int _s = 0; _s < 8; ++_s) {                                      \
            buf_[_s]     = *(const f16x8*)(_p0 + _s * 32);                    \
            buf_[8 + _s] = *(const f16x8*)(_p1 + _s * 32);                    \
        } } while (0)

#define MF(buf_, a0_, a1_) do {                                               \
        _Pragma("unroll")                                                     \
        for (int _s = 0; _s < 8; ++_s) {                                      \
            a0_ = __builtin_amdgcn_mfma_f32_16x16x32_f16(ah[_s], buf_[_s],     a0_, 0, 0, 0); \
            a0_ = __builtin_amdgcn_mfma_f32_16x16x32_f16(al[_s], buf_[_s],     a0_, 0, 0, 0); \
            a1_ = __builtin_amdgcn_mfma_f32_16x16x32_f16(ah[_s], buf_[8 + _s], a1_, 0, 0, 0); \
            a1_ = __builtin_amdgcn_mfma_f32_16x16x32_f16(al[_s], buf_[8 + _s], a1_, 0, 0, 0); \
        } } while (0)

#define CSUM(buf_, nf_) do {                                                  \
        f32x4 _a0 = (f32x4)0.f, _a1 = (f32x4)0.f;                             \
        MF(buf_, _a0, _a1);                                                   \
        const float _v0 = vp[(nf_) * 16], _v1 = vp[(nf_) * 16 + 16];          \
        _Pragma("unroll")                                                     \
        for (int _r = 0; _r < 4; ++_r) {                                      \
            const float _u0 = __expf(_a0[_r] - SHIFT);                        \
            const float _u1 = __expf(_a1[_r] - SHIFT);                        \
            rs[_r] += _u0 + _u1;                                              \
            rd[_r] += _u0 * _v0 + _u1 * _v1;                                  \
        } } while (0)

#define CST(buf_, nf_) do {                                                   \
        f32x4 _a0 = (f32x4)0.f, _a1 = (f32x4)0.f;                             \
        MF(buf_, _a0, _a1);                                                   \
        float4 _u;                                                            \
        _u.x = __expf(_a0[0] - SHIFT) * iv[0];                                \
        _u.y = __expf(_a0[1] - SHIFT) * iv[1];                                \
        _u.z = __expf(_a0[2] - SHIFT) * iv[2];                                \
        _u.w = __expf(_a0[3] - SHIFT) * iv[3];                                \
        *(float4*)(outw + (size_t)(nf_) * 16 * NDIM) = _u;                    \
        _u.x = __expf(_a1[0] - SHIFT) * iv[0];                                \
        _u.y = __expf(_a1[1] - SHIFT) * iv[1];                                \
        _u.z = __expf(_a1[2] - SHIFT) * iv[2];                                \
        _u.w = __expf(_a1[3] - SHIFT) * iv[3];                                \
        *(float4*)(outw + (size_t)(nf_ + 1) * 16 * NDIM) = _u;                \
    } while (0)

    // ---------------- pass 1: row sums/dots ----------------
    LOADP(bx, 0);
#pragma unroll 1
    for (int nf = 0; nf < 64; nf += 4) {
        LOADP(by, nf + 2);
        CSUM(bx, nf);
        if (nf + 4 < 64) LOADP(bx, nf + 4);
        CSUM(by, nf + 2);
    }

    // reduce over the 16 ll lanes (n within frag)
#pragma unroll
    for (int r = 0; r < 4; ++r)
#pragma unroll
        for (int off = 1; off < 16; off <<= 1) {
            rs[r] += __shfl_xor(rs[r], off);
            rd[r] += __shfl_xor(rd[r], off);
        }

    __shared__ float redS[4][4][4], redD[4][4][4];   // [wv][lq][r]
    if (ll == 0)
#pragma unroll
        for (int r = 0; r < 4; ++r) { redS[wv][lq][r] = rs[r]; redD[wv][lq][r] = rd[r]; }
    __syncthreads();

#pragma unroll
    for (int r = 0; r < 4; ++r) {
        const float ssum = redS[0][lq][r] + redS[1][lq][r] + redS[2][lq][r] + redS[3][lq][r];
        iv[r] = 1.0f / ssum;
    }
    if (wv == 0 && ll == 0) {
#pragma unroll
        for (int r = 0; r < 4; ++r) {
            const float dsum = redD[0][lq][r] + redD[1][lq][r] + redD[2][lq][r] + redD[3][lq][r];
            const float xx = dsum * iv[r];
            outMask[bb * NDIM + m0 + lq * 4 + r] = 1.0f / (1.0f + __expf(-xx));
        }
    }

    // ---------------- pass 2: recompute + normalized store ----------------
    LOADP(bx, 0);
#pragma unroll 1
    for (int nf = 0; nf < 64; nf += 4) {
        LOADP(by, nf + 2);
        CST(bx, nf);
        if (nf + 4 < 64) LOADP(bx, nf + 4);
        CST(by, nf + 2);
    }

#undef LOADP
#undef MF
#undef CSUM
#undef CST
}

// ---------------------------------------------------------------------------
extern "C" void kernel_launch(void* const* d_in, const int* in_sizes, int n_in,
                              void* d_out, int out_size, void* d_ws, size_t ws_size,
                              hipStream_t stream)
{
    const float* ex   = (const float*)d_in[0];
    const float* q    = (const float*)d_in[1];
    const float* W_ex = (const float*)d_in[2];
    const float* W_q  = (const float*)d_in[3];
    const float* g    = (const float*)d_in[4];
    float* outp = (float*)d_out;

    float* A_e2q = outp + 16384;
    float* A_q2e = A_e2q + (size_t)BSZ * NDIM * NDIM;

    // e2q operands parked in the A_q2e region (consumed before it is written)
    f16* Ah_e = (f16*)A_q2e;
    f16* Al_e = Ah_e + F16N;
    f16* Bq   = Al_e + F16N;

    // q2e operands + small arrays in workspace
    f16* Ah_q = (f16*)d_ws;
    f16* Al_q = Ah_q + F16N;
    f16* Bex  = Al_q + F16N;
    float* wsf  = (float*)d_ws + WS_FB;
    float* v_ex = wsf;
    float* v_q  = wsf + 8192;

    corr_kernel<<<dim3(NDIM / 128, CDIM / 128, 2 * BSZ), 256, 0, stream>>>(
        ex, q, W_ex, W_q, Ah_e, Al_e, Ah_q, Al_q);

    pack_b_kernel<<<dim3(NDIM / 64, CDIM / 64, 2 * BSZ), 256, 0, stream>>>(
        ex, q, Bq, Bex);

    v_kernel<<<dim3(NDIM / 256, BSZ, 2), 256, 0, stream>>>(ex, q, g, v_ex, v_q);

    // e2q: S = ex_corr . q ; mask (ex_mask) uses v_ex. Consumes the park.
    flash_score_kernel<<<dim3(256, BSZ), 256, 0, stream>>>(
        Ah_e, Al_e, Bq, v_ex, A_e2q, outp);
    // q2e: S = q_corr . ex ; mask (q_mask) uses v_q. Overwrites the park.
    flash_score_kernel<<<dim3(256, BSZ), 256, 0, stream>>>(
        Ah_q, Al_q, Bex, v_q, A_q2e, outp + 8192);
}